// Round 2
// baseline (310.286 us; speedup 1.0000x reference)
//
#include <hip/hip_runtime.h>
#include <math.h>

#define N_HITS 65536
#define K_INST 512
#define MARGIN 0.3f
#define BPB    128      // blocks per batch in main kernel -> 2048 blocks total

// ---------------------------------------------------------------------------
// Kernel 1: fused scan + gather. One block per batch, 1024 threads.
// first_cp lives in LDS (sentinel N_HITS), pos counted locally, then cp rows
// gathered to global. Eliminates the 0x7F memset and one dispatch.
// ---------------------------------------------------------------------------
__global__ __launch_bounds__(1024) void k_prep(
    const float* __restrict__ beta, const float4* __restrict__ embed4,
    const int* __restrict__ sid, const int* __restrict__ iscp,
    int* first_cp_g, int* pos_cnt, float* cp_beta, float4* cp_emb4) {
    __shared__ int lfc[K_INST];
    __shared__ int lpos[16];
    int b = blockIdx.x, tid = threadIdx.x;
    for (int k = tid; k < K_INST; k += 1024) lfc[k] = N_HITS;
    __syncthreads();

    size_t bo = (size_t)b * N_HITS;
    int pos = 0;
    for (int i = tid; i < N_HITS; i += 1024) {
        int c = iscp[bo + i];
        if (c == 1) {
            pos++;
            int s = sid[bo + i];
            if (s >= 0) atomicMin(&lfc[s], i);
        }
    }
    for (int o = 32; o > 0; o >>= 1) pos += __shfl_down(pos, o);
    if ((tid & 63) == 0) lpos[tid >> 6] = pos;
    __syncthreads();   // also publishes all lfc atomicMins
    if (tid == 0) {
        int t = 0;
        for (int w = 0; w < 16; ++w) t += lpos[w];
        pos_cnt[b] = t;
    }
    // gather: 8 lanes per cp row
    int sub = tid & 7;
    for (int r = tid >> 3; r < K_INST; r += 128) {
        int fc = lfc[r];
        int safe = min(fc, N_HITS - 1);
        cp_emb4[((size_t)b * K_INST + r) * 8 + sub] = embed4[(bo + safe) * 8 + sub];
        if (sub == 0) {
            cp_beta[b * K_INST + r] = beta[bo + safe];
            first_cp_g[b * K_INST + r] = fc;
        }
    }
}

// ---------------------------------------------------------------------------
// Kernel 2: main streaming pass. 8 lanes per hit, LDS segment bins,
// software-pipelined loads, 2048 blocks for full occupancy.
// ---------------------------------------------------------------------------
__global__ __launch_bounds__(256) void k_main(
    const float*  __restrict__ beta,  const float4* __restrict__ embed4,
    const int*    __restrict__ sid_g, const int*    __restrict__ iscp_g,
    const float4* __restrict__ cp_emb4, const float* __restrict__ cp_beta,
    int* cnt_packed, float* seg_d2, float* seg_r,
    float* s_cp, float* s_ncp, float* s_bg) {
    __shared__ int   l_cnt[K_INST];
    __shared__ float l_d2[K_INST];
    __shared__ float l_r[K_INST];
    __shared__ float l_red[12];

    int b = blockIdx.y, tid = threadIdx.x;
    for (int k = tid; k < K_INST; k += 256) { l_cnt[k] = 0; l_d2[k] = 0.f; l_r[k] = 0.f; }
    __syncthreads();

    int sub = tid & 7, hid = tid >> 3;         // 8 lanes per hit, 32 hits/iter
    const int hits = N_HITS / BPB;             // 512
    const int iters = hits / 32;               // 16
    size_t bo = (size_t)b * N_HITS;
    int base = blockIdx.x * hits;
    float a_cp = 0.f, a_ncp = 0.f, a_bg = 0.f;

    // pipeline prologue
    int i = base + hid;
    int s = sid_g[bo + i];
    int c = iscp_g[bo + i];
    float4 e = embed4[(bo + i) * 8 + sub];
    float x = beta[bo + i];

    for (int it = 0; it < iters; ++it) {
        // prefetch next iteration before consuming current
        int inext = i + 32;
        int s2 = 0, c2 = 0; float4 e2 = make_float4(0.f, 0.f, 0.f, 0.f); float x2 = 0.f;
        if (it + 1 < iters) {
            s2 = sid_g[bo + inext];
            c2 = iscp_g[bo + inext];
            e2 = embed4[(bo + inext) * 8 + sub];
            x2 = beta[bo + inext];
        }

        bool cp = (c == 1), valid = (s >= 0), noncp = valid && !cp;
        int sc = min(max(s, 0), K_INST - 1);
        float4 ce = cp_emb4[((size_t)b * K_INST + sc) * 8 + sub];
        float dx = e.x - ce.x, dy = e.y - ce.y, dz = e.z - ce.z, dw = e.w - ce.w;
        float d2 = dx * dx + dy * dy + dz * dz + dw * dw;
        d2 += __shfl_xor(d2, 1);
        d2 += __shfl_xor(d2, 2);
        d2 += __shfl_xor(d2, 4);

        if (sub == 0) {
            float bce = fmaxf(x, 0.f) - (cp ? x : 0.f) + log1pf(__expf(-fabsf(x)));
            if (cp) a_cp += bce; else if (noncp) a_ncp += bce; else a_bg += bce;
            if (valid) {
                atomicAdd(&l_cnt[s], cp ? (1 << 20) : 1);
                atomicAdd(&l_d2[s], d2);
                if (noncp) {
                    float r = fmaxf(x + MARGIN - cp_beta[b * K_INST + s], 0.f);
                    atomicAdd(&l_r[s], r);
                }
            }
        }
        i = inext; s = s2; c = c2; e = e2; x = x2;
    }

    // block-reduce the three BCE class sums
    for (int o = 32; o > 0; o >>= 1) {
        a_cp  += __shfl_down(a_cp, o);
        a_ncp += __shfl_down(a_ncp, o);
        a_bg  += __shfl_down(a_bg, o);
    }
    int wave = tid >> 6;
    if ((tid & 63) == 0) { l_red[wave] = a_cp; l_red[4 + wave] = a_ncp; l_red[8 + wave] = a_bg; }
    __syncthreads();
    if (tid == 0) {
        atomicAdd(&s_cp[b],  l_red[0] + l_red[1] + l_red[2]  + l_red[3]);
        atomicAdd(&s_ncp[b], l_red[4] + l_red[5] + l_red[6]  + l_red[7]);
        atomicAdd(&s_bg[b],  l_red[8] + l_red[9] + l_red[10] + l_red[11]);
    }
    // merge LDS bins to global
    for (int k = tid; k < K_INST; k += 256) {
        int   cv = l_cnt[k]; if (cv)        atomicAdd(&cnt_packed[b * K_INST + k], cv);
        float dv = l_d2[k];  if (dv != 0.f) atomicAdd(&seg_d2[b * K_INST + k], dv);
        float rv = l_r[k];   if (rv != 0.f) atomicAdd(&seg_r[b * K_INST + k], rv);
    }
}

// ---------------------------------------------------------------------------
// Kernel 3: fused tail. Blocks [0, B*16): repulsion tiles. Blocks
// [B*16, B*16+B): per-segment finalize. Last block to finish (device-scope
// atomic ticket) combines everything and writes the 4 outputs.
// ---------------------------------------------------------------------------
__global__ __launch_bounds__(512) void k_tail(
    const float4* __restrict__ cp_emb4,
    const int* __restrict__ cnt_packed, const float* __restrict__ seg_d2,
    const float* __restrict__ seg_r, const int* __restrict__ first_cp,
    const int* __restrict__ pos_cnt, const float* __restrict__ s_cp,
    const float* __restrict__ s_ncp, const float* __restrict__ s_bg,
    float* attr_b, float* rank_b, float* nuniq_b, float* rep_b,
    int* ctr, float* out, int B) {
    int tid = threadIdx.x;
    int nrep = B * 16;

    if ((int)blockIdx.x < nrep) {
        // --- repulsion: 512 k1-rows (1/thread) x 32-row k2 LDS tile ---
        __shared__ float4 tile[32 * 8];
        __shared__ float red[8];
        int b = blockIdx.x >> 4, t2 = blockIdx.x & 15;
        const float4* base = cp_emb4 + (size_t)b * K_INST * 8;
        float4 r0[8];
#pragma unroll
        for (int cc = 0; cc < 8; ++cc) r0[cc] = base[(size_t)tid * 8 + cc];
        if (tid < 256) tile[tid] = base[(size_t)t2 * 256 + tid];
        __syncthreads();
        float acc = 0.f;
        for (int j = 0; j < 32; ++j) {
            float d2 = 0.f;
#pragma unroll
            for (int cc = 0; cc < 8; ++cc) {
                float4 ev = tile[j * 8 + cc];
                float ax = r0[cc].x - ev.x, ay = r0[cc].y - ev.y;
                float az = r0[cc].z - ev.z, aw = r0[cc].w - ev.w;
                d2 += ax * ax + ay * ay + az * az + aw * aw;
            }
            acc += __expf(-d2);
        }
        for (int o = 32; o > 0; o >>= 1) acc += __shfl_down(acc, o);
        if ((tid & 63) == 0) red[tid >> 6] = acc;
        __syncthreads();
        if (tid == 0) {
            float t = 0.f;
            for (int w = 0; w < 8; ++w) t += red[w];
            atomicAdd(&rep_b[b], t);
        }
    } else {
        // --- per-segment finalize, thread = segment ---
        __shared__ float red2[3][8];
        int b = blockIdx.x - nrep, k = tid;
        int v = cnt_packed[b * K_INST + k];
        int ncp = v & 0xFFFFF, cpc = v >> 20;
        int counts = ncp + cpc;
        int fc = first_cp[b * K_INST + k];
        bool has_cp = fc < N_HITS, exists = counts > 0;
        float attr = (has_cp && exists) ? seg_d2[b * K_INST + k] / fmaxf((float)counts, 1.f) : 0.f;
        float rank = (cpc == 1 && ncp > 0) ? seg_r[b * K_INST + k] / fmaxf((float)ncp, 1.f) : 0.f;
        float uq = exists ? 1.f : 0.f;
        for (int o = 32; o > 0; o >>= 1) {
            attr += __shfl_down(attr, o);
            rank += __shfl_down(rank, o);
            uq   += __shfl_down(uq, o);
        }
        if ((k & 63) == 0) { red2[0][k >> 6] = attr; red2[1][k >> 6] = rank; red2[2][k >> 6] = uq; }
        __syncthreads();
        if (k == 0) {
            float a = 0.f, r = 0.f, u = 0.f;
            for (int w = 0; w < 8; ++w) { a += red2[0][w]; r += red2[1][w]; u += red2[2][w]; }
            attr_b[b] = a; rank_b[b] = r; nuniq_b[b] = u;
        }
    }

    // --- completion ticket; last block combines ---
    __shared__ int is_last;
    __syncthreads();
    if (tid == 0) {
        __threadfence();                       // publish this block's results
        int v = atomicAdd(ctr, 1);             // device-scope
        is_last = (v == (int)gridDim.x - 1);
    }
    __syncthreads();
    if (is_last) {
        __threadfence();                       // acquire other blocks' results
        if (tid < 64) {
            int b = tid;
            float loss = 0.f, bl = 0.f, at = 0.f, rp = 0.f;
            if (b < B) {
                float pos = (float)pos_cnt[b];
                float pw = ((float)N_HITS - pos) / (pos + 1e-6f);
                float bce = (pw * s_cp[b] + s_ncp[b] + 2.f * s_bg[b]) / (float)N_HITS;
                float rank = rank_b[b] / fmaxf(nuniq_b[b], 1.f);
                bl = bce + 2.f * rank;
                at = attr_b[b];
                rp = rep_b[b] / (float)(K_INST * K_INST);
                loss = bl + at + rp;
            }
            for (int o = 32; o > 0; o >>= 1) {
                loss += __shfl_down(loss, o);
                bl   += __shfl_down(bl, o);
                at   += __shfl_down(at, o);
                rp   += __shfl_down(rp, o);
            }
            if (tid == 0) {
                float inv = 1.f / (float)B;
                out[0] = loss * inv;
                out[1] = bl * inv;
                out[2] = at * inv;
                out[3] = rp * inv;
            }
        }
    }
}

// ---------------------------------------------------------------------------
extern "C" void kernel_launch(void* const* d_in, const int* in_sizes, int n_in,
                              void* d_out, int out_size, void* d_ws, size_t ws_size,
                              hipStream_t stream) {
    const float*  beta   = (const float*)d_in[0];
    const float*  embed  = (const float*)d_in[1];
    const int*    sid    = (const int*)d_in[2];
    const int*    iscp   = (const int*)d_in[3];
    float* out = (float*)d_out;

    int BN = in_sizes[0];          // B*N
    int B  = BN / N_HITS;          // 16
    int BK = B * K_INST;           // 8192

    // workspace layout (bytes):
    //   zeroed region:
    //     [0,        4*BK)       cnt_packed
    //     [4*BK,     8*BK)       seg_d2
    //     [8*BK,    12*BK)       seg_r
    //     [12*BK, +32*B)         per-batch scalars: pos,scp,sncp,sbg,attr,rank,nuniq,rep
    //     [.., +16)              ctr (+pad)
    //   written-by-kernel region:
    //     first_cp (4*BK), cp_beta (4*BK), cp_emb (128*BK)
    char* ws = (char*)d_ws;
    int*   cnt_packed = (int*)ws;
    float* seg_d2     = (float*)(ws + 4 * (size_t)BK);
    float* seg_r      = (float*)(ws + 8 * (size_t)BK);
    float* scal       = (float*)(ws + 12 * (size_t)BK);
    int*   pos_cnt  = (int*)scal;
    float* s_cp     = scal + 1 * B;
    float* s_ncp    = scal + 2 * B;
    float* s_bg     = scal + 3 * B;
    float* attr_b   = scal + 4 * B;
    float* rank_b   = scal + 5 * B;
    float* nuniq_b  = scal + 6 * B;
    float* rep_b    = scal + 7 * B;
    int*   ctr      = (int*)(scal + 8 * B);
    size_t zbytes = 12 * (size_t)BK + 32 * (size_t)B + 16;   // 98832 for B=16
    int*    first_cp = (int*)(ws + zbytes);
    float*  cp_beta  = (float*)(ws + zbytes + 4 * (size_t)BK);
    float4* cp_emb4  = (float4*)(ws + zbytes + 8 * (size_t)BK);  // 16B-aligned

    hipMemsetAsync(ws, 0, zbytes, stream);

    // 1: fused scan + gather
    k_prep<<<B, 1024, 0, stream>>>(beta, (const float4*)embed, sid, iscp,
                                   first_cp, pos_cnt, cp_beta, cp_emb4);

    // 2: main streaming pass (full occupancy, pipelined)
    k_main<<<dim3(BPB, B), 256, 0, stream>>>(beta, (const float4*)embed, sid, iscp,
                                             (const float4*)cp_emb4, cp_beta,
                                             cnt_packed, seg_d2, seg_r, s_cp, s_ncp, s_bg);

    // 3: fused seg-finalize + repulsion + final combine
    k_tail<<<B * 16 + B, 512, 0, stream>>>(cp_emb4, cnt_packed, seg_d2, seg_r,
                                           first_cp, pos_cnt, s_cp, s_ncp, s_bg,
                                           attr_b, rank_b, nuniq_b, rep_b,
                                           ctr, out, B);
}

// Round 3
// 291.723 us; speedup vs baseline: 1.0636x; 1.0636x over previous
//
#include <hip/hip_runtime.h>
#include <math.h>

#define N_HITS 65536
#define K_INST 512
#define MARGIN 0.3f
#define BPB    128      // blocks per batch -> 2048 blocks total (8/CU)
#define HITS_PB (N_HITS / BPB)   // 512
#define ITERS   (HITS_PB / 32)   // 16

// ---------------------------------------------------------------------------
// Kernel 1: fused scan + gather. One block per batch, 1024 threads.
// ---------------------------------------------------------------------------
__global__ __launch_bounds__(1024) void k_prep(
    const float* __restrict__ beta, const float4* __restrict__ embed4,
    const int* __restrict__ sid, const int* __restrict__ iscp,
    int* first_cp_g, int* pos_cnt, float* cp_beta, float4* cp_emb4) {
    __shared__ int lfc[K_INST];
    __shared__ int lpos[16];
    int b = blockIdx.x, tid = threadIdx.x;
    for (int k = tid; k < K_INST; k += 1024) lfc[k] = N_HITS;
    __syncthreads();

    size_t bo = (size_t)b * N_HITS;
    int pos = 0;
    for (int i = tid; i < N_HITS; i += 1024) {
        int c = iscp[bo + i];
        if (c == 1) {
            pos++;
            int s = sid[bo + i];
            if (s >= 0) atomicMin(&lfc[s], i);
        }
    }
    for (int o = 32; o > 0; o >>= 1) pos += __shfl_down(pos, o);
    if ((tid & 63) == 0) lpos[tid >> 6] = pos;
    __syncthreads();
    if (tid == 0) {
        int t = 0;
        for (int w = 0; w < 16; ++w) t += lpos[w];
        pos_cnt[b] = t;
    }
    int sub = tid & 7;
    for (int r = tid >> 3; r < K_INST; r += 128) {
        int fc = lfc[r];
        int safe = min(fc, N_HITS - 1);
        cp_emb4[((size_t)b * K_INST + r) * 8 + sub] = embed4[(bo + safe) * 8 + sub];
        if (sub == 0) {
            cp_beta[b * K_INST + r] = beta[bo + safe];
            first_cp_g[b * K_INST + r] = fc;
        }
    }
}

// ---------------------------------------------------------------------------
// Kernel 2: main streaming pass.
// Scalars (sid/iscp/beta/cp_beta) staged in LDS once per block; inner loop
// has only 2 global loads: e (depth-2 prefetch) and ce (depth-1, address from
// LDS). Issue order keeps prefetches in flight (vmcnt(2), never vmcnt(0)).
// ---------------------------------------------------------------------------
__global__ __launch_bounds__(256) void k_main(
    const float*  __restrict__ beta,  const float4* __restrict__ embed4,
    const int*    __restrict__ sid_g, const int*    __restrict__ iscp_g,
    const float4* __restrict__ cp_emb4, const float* __restrict__ cp_beta,
    int* cnt_packed, float* seg_d2, float* seg_r,
    float* s_cp, float* s_ncp, float* s_bg) {
    __shared__ int   l_cnt[K_INST];
    __shared__ float l_d2[K_INST];
    __shared__ float l_r[K_INST];
    __shared__ float l_cb[K_INST];
    __shared__ int   st_sc[HITS_PB];
    __shared__ float st_x[HITS_PB];
    __shared__ float l_red[12];

    int b = blockIdx.y, tid = threadIdx.x;
    size_t bo = (size_t)b * N_HITS;
    int base = blockIdx.x * HITS_PB;

    // bin init + stage scalars (coalesced)
    for (int k = tid; k < K_INST; k += 256) {
        l_cnt[k] = 0; l_d2[k] = 0.f; l_r[k] = 0.f;
        l_cb[k] = cp_beta[b * K_INST + k];
    }
    for (int k = tid; k < HITS_PB; k += 256) {
        int s = sid_g[bo + base + k];
        int c = iscp_g[bo + base + k];
        st_sc[k] = (s << 1) | (c & 1);
        st_x[k]  = beta[bo + base + k];
    }
    __syncthreads();

    int sub = tid & 7, hid = tid >> 3;     // 8 lanes/hit, 32 hits/iter
    const float4* cpe = cp_emb4 + (size_t)b * K_INST * 8;

    // software pipeline: e at depth 2, ce at depth 1
    float4 eA, eB, ceA;
    int scA, scB;
    {
        int i0 = base + hid, i1 = base + 32 + hid;
        eA = embed4[(bo + i0) * 8 + sub];
        eB = embed4[(bo + i1) * 8 + sub];
        scA = st_sc[hid];
        scB = st_sc[32 + hid];
        int cl = min(max(scA >> 1, 0), K_INST - 1);
        ceA = cpe[(size_t)cl * 8 + sub];
    }

    float a_cp = 0.f, a_ncp = 0.f, a_bg = 0.f;

    for (int it = 0; it < ITERS; ++it) {
        // issue e(it+2) first, then ce(it+1): consuming ce(it) then needs
        // only vmcnt(2) -> next-iter prefetches stay in flight
        float4 e2 = make_float4(0.f, 0.f, 0.f, 0.f);
        if (it + 2 < ITERS)
            e2 = embed4[(bo + base + (it + 2) * 32 + hid) * 8 + sub];
        float4 ceN = make_float4(0.f, 0.f, 0.f, 0.f);
        if (it + 1 < ITERS) {
            int cl1 = min(max(scB >> 1, 0), K_INST - 1);
            ceN = cpe[(size_t)cl1 * 8 + sub];
        }
        int sc2n = (it + 2 < ITERS) ? st_sc[(it + 2) * 32 + hid] : 0;

        // consume current
        int sc = scA, s = sc >> 1;
        bool cp = (sc & 1), valid = (s >= 0), noncp = valid && !cp;
        float dx = eA.x - ceA.x, dy = eA.y - ceA.y;
        float dz = eA.z - ceA.z, dw = eA.w - ceA.w;
        float d2 = dx * dx + dy * dy + dz * dz + dw * dw;
        d2 += __shfl_xor(d2, 1);
        d2 += __shfl_xor(d2, 2);
        d2 += __shfl_xor(d2, 4);

        if (sub == 0) {
            float x = st_x[it * 32 + hid];
            float t = __expf(-fabsf(x));
            float bce = fmaxf(x, 0.f) - (cp ? x : 0.f) + __logf(1.f + t);
            if (cp) a_cp += bce; else if (noncp) a_ncp += bce; else a_bg += bce;
            if (valid) {
                atomicAdd(&l_cnt[s], cp ? (1 << 20) : 1);
                atomicAdd(&l_d2[s], d2);
                if (noncp) {
                    float r = fmaxf(x + MARGIN - l_cb[s], 0.f);
                    atomicAdd(&l_r[s], r);
                }
            }
        }
        // rotate pipeline
        eA = eB; eB = e2; ceA = ceN; scA = scB; scB = sc2n;
    }

    // block-reduce the three BCE class sums
    for (int o = 32; o > 0; o >>= 1) {
        a_cp  += __shfl_down(a_cp, o);
        a_ncp += __shfl_down(a_ncp, o);
        a_bg  += __shfl_down(a_bg, o);
    }
    int wave = tid >> 6;
    if ((tid & 63) == 0) { l_red[wave] = a_cp; l_red[4 + wave] = a_ncp; l_red[8 + wave] = a_bg; }
    __syncthreads();
    if (tid == 0) {
        atomicAdd(&s_cp[b],  l_red[0] + l_red[1] + l_red[2]  + l_red[3]);
        atomicAdd(&s_ncp[b], l_red[4] + l_red[5] + l_red[6]  + l_red[7]);
        atomicAdd(&s_bg[b],  l_red[8] + l_red[9] + l_red[10] + l_red[11]);
    }
    // merge LDS bins to global
    for (int k = tid; k < K_INST; k += 256) {
        int   cv = l_cnt[k]; if (cv)        atomicAdd(&cnt_packed[b * K_INST + k], cv);
        float dv = l_d2[k];  if (dv != 0.f) atomicAdd(&seg_d2[b * K_INST + k], dv);
        float rv = l_r[k];   if (rv != 0.f) atomicAdd(&seg_r[b * K_INST + k], rv);
    }
}

// ---------------------------------------------------------------------------
// Kernel 3: fused tail: repulsion tiles + seg finalize + last-block combine.
// ---------------------------------------------------------------------------
__global__ __launch_bounds__(512) void k_tail(
    const float4* __restrict__ cp_emb4,
    const int* __restrict__ cnt_packed, const float* __restrict__ seg_d2,
    const float* __restrict__ seg_r, const int* __restrict__ first_cp,
    const int* __restrict__ pos_cnt, const float* __restrict__ s_cp,
    const float* __restrict__ s_ncp, const float* __restrict__ s_bg,
    float* attr_b, float* rank_b, float* nuniq_b, float* rep_b,
    int* ctr, float* out, int B) {
    int tid = threadIdx.x;
    int nrep = B * 16;

    if ((int)blockIdx.x < nrep) {
        __shared__ float4 tile[32 * 8];
        __shared__ float red[8];
        int b = blockIdx.x >> 4, t2 = blockIdx.x & 15;
        const float4* base = cp_emb4 + (size_t)b * K_INST * 8;
        float4 r0[8];
#pragma unroll
        for (int cc = 0; cc < 8; ++cc) r0[cc] = base[(size_t)tid * 8 + cc];
        if (tid < 256) tile[tid] = base[(size_t)t2 * 256 + tid];
        __syncthreads();
        float acc = 0.f;
        for (int j = 0; j < 32; ++j) {
            float d2 = 0.f;
#pragma unroll
            for (int cc = 0; cc < 8; ++cc) {
                float4 ev = tile[j * 8 + cc];
                float ax = r0[cc].x - ev.x, ay = r0[cc].y - ev.y;
                float az = r0[cc].z - ev.z, aw = r0[cc].w - ev.w;
                d2 += ax * ax + ay * ay + az * az + aw * aw;
            }
            acc += __expf(-d2);
        }
        for (int o = 32; o > 0; o >>= 1) acc += __shfl_down(acc, o);
        if ((tid & 63) == 0) red[tid >> 6] = acc;
        __syncthreads();
        if (tid == 0) {
            float t = 0.f;
            for (int w = 0; w < 8; ++w) t += red[w];
            atomicAdd(&rep_b[b], t);
        }
    } else {
        __shared__ float red2[3][8];
        int b = blockIdx.x - nrep, k = tid;
        int v = cnt_packed[b * K_INST + k];
        int ncp = v & 0xFFFFF, cpc = v >> 20;
        int counts = ncp + cpc;
        int fc = first_cp[b * K_INST + k];
        bool has_cp = fc < N_HITS, exists = counts > 0;
        float attr = (has_cp && exists) ? seg_d2[b * K_INST + k] / fmaxf((float)counts, 1.f) : 0.f;
        float rank = (cpc == 1 && ncp > 0) ? seg_r[b * K_INST + k] / fmaxf((float)ncp, 1.f) : 0.f;
        float uq = exists ? 1.f : 0.f;
        for (int o = 32; o > 0; o >>= 1) {
            attr += __shfl_down(attr, o);
            rank += __shfl_down(rank, o);
            uq   += __shfl_down(uq, o);
        }
        if ((k & 63) == 0) { red2[0][k >> 6] = attr; red2[1][k >> 6] = rank; red2[2][k >> 6] = uq; }
        __syncthreads();
        if (k == 0) {
            float a = 0.f, r = 0.f, u = 0.f;
            for (int w = 0; w < 8; ++w) { a += red2[0][w]; r += red2[1][w]; u += red2[2][w]; }
            attr_b[b] = a; rank_b[b] = r; nuniq_b[b] = u;
        }
    }

    __shared__ int is_last;
    __syncthreads();
    if (tid == 0) {
        __threadfence();
        int v = atomicAdd(ctr, 1);
        is_last = (v == (int)gridDim.x - 1);
    }
    __syncthreads();
    if (is_last) {
        __threadfence();
        if (tid < 64) {
            int b = tid;
            float loss = 0.f, bl = 0.f, at = 0.f, rp = 0.f;
            if (b < B) {
                float pos = (float)pos_cnt[b];
                float pw = ((float)N_HITS - pos) / (pos + 1e-6f);
                float bce = (pw * s_cp[b] + s_ncp[b] + 2.f * s_bg[b]) / (float)N_HITS;
                float rank = rank_b[b] / fmaxf(nuniq_b[b], 1.f);
                bl = bce + 2.f * rank;
                at = attr_b[b];
                rp = rep_b[b] / (float)(K_INST * K_INST);
                loss = bl + at + rp;
            }
            for (int o = 32; o > 0; o >>= 1) {
                loss += __shfl_down(loss, o);
                bl   += __shfl_down(bl, o);
                at   += __shfl_down(at, o);
                rp   += __shfl_down(rp, o);
            }
            if (tid == 0) {
                float inv = 1.f / (float)B;
                out[0] = loss * inv;
                out[1] = bl * inv;
                out[2] = at * inv;
                out[3] = rp * inv;
            }
        }
    }
}

// ---------------------------------------------------------------------------
extern "C" void kernel_launch(void* const* d_in, const int* in_sizes, int n_in,
                              void* d_out, int out_size, void* d_ws, size_t ws_size,
                              hipStream_t stream) {
    const float*  beta   = (const float*)d_in[0];
    const float*  embed  = (const float*)d_in[1];
    const int*    sid    = (const int*)d_in[2];
    const int*    iscp   = (const int*)d_in[3];
    float* out = (float*)d_out;

    int BN = in_sizes[0];          // B*N
    int B  = BN / N_HITS;          // 16
    int BK = B * K_INST;           // 8192

    char* ws = (char*)d_ws;
    int*   cnt_packed = (int*)ws;
    float* seg_d2     = (float*)(ws + 4 * (size_t)BK);
    float* seg_r      = (float*)(ws + 8 * (size_t)BK);
    float* scal       = (float*)(ws + 12 * (size_t)BK);
    int*   pos_cnt  = (int*)scal;
    float* s_cp     = scal + 1 * B;
    float* s_ncp    = scal + 2 * B;
    float* s_bg     = scal + 3 * B;
    float* attr_b   = scal + 4 * B;
    float* rank_b   = scal + 5 * B;
    float* nuniq_b  = scal + 6 * B;
    float* rep_b    = scal + 7 * B;
    int*   ctr      = (int*)(scal + 8 * B);
    size_t zbytes = 12 * (size_t)BK + 32 * (size_t)B + 16;
    int*    first_cp = (int*)(ws + zbytes);
    float*  cp_beta  = (float*)(ws + zbytes + 4 * (size_t)BK);
    float4* cp_emb4  = (float4*)(ws + zbytes + 8 * (size_t)BK);

    hipMemsetAsync(ws, 0, zbytes, stream);

    k_prep<<<B, 1024, 0, stream>>>(beta, (const float4*)embed, sid, iscp,
                                   first_cp, pos_cnt, cp_beta, cp_emb4);

    k_main<<<dim3(BPB, B), 256, 0, stream>>>(beta, (const float4*)embed, sid, iscp,
                                             (const float4*)cp_emb4, cp_beta,
                                             cnt_packed, seg_d2, seg_r, s_cp, s_ncp, s_bg);

    k_tail<<<B * 16 + B, 512, 0, stream>>>(cp_emb4, cnt_packed, seg_d2, seg_r,
                                           first_cp, pos_cnt, s_cp, s_ncp, s_bg,
                                           attr_b, rank_b, nuniq_b, rep_b,
                                           ctr, out, B);
}

// Round 4
// 261.746 us; speedup vs baseline: 1.1854x; 1.1145x over previous
//
#include <hip/hip_runtime.h>
#include <math.h>

#define N_HITS 65536
#define K_INST 512
#define MARGIN 0.3f
#define BPB    128               // blocks per batch -> 2048 blocks total
#define HITS_PB (N_HITS / BPB)   // 512 hits per block, 2 per thread

// ---------------------------------------------------------------------------
// Kernel 1: first_cp via global atomicMin + pos count. 512 blocks.
// first_cp pre-memset to 0x7F7F7F7F (> N_HITS sentinel).
// ---------------------------------------------------------------------------
__global__ __launch_bounds__(256) void k_scan(
    const int* __restrict__ sid, const int* __restrict__ iscp,
    int* first_cp, int* pos_cnt) {
    int b = blockIdx.y;
    size_t bo = (size_t)b * N_HITS;
    int i = blockIdx.x * 256 + threadIdx.x;
    int stride = gridDim.x * 256;
    for (; i < N_HITS; i += stride) {
        int c = iscp[bo + i];
        if (c == 1) {
            atomicAdd(&pos_cnt[b], 1);   // compiler coalesces per-wave
            int s = sid[bo + i];
            if (s >= 0) atomicMin(&first_cp[b * K_INST + s], i);
        }
    }
}

// ---------------------------------------------------------------------------
// Kernel 2: gather cp_emb / cp_beta with safe_cp = min(first_cp, N-1)
// ---------------------------------------------------------------------------
__global__ __launch_bounds__(256) void k_gather(
    const float* __restrict__ beta, const float4* __restrict__ embed4,
    const int* __restrict__ first_cp,
    float* cp_beta, float4* cp_emb4, int B) {
    int g = blockIdx.x * 256 + threadIdx.x;
    int total = B * K_INST * 8;
    if (g >= total) return;
    int row = g >> 3, sub = g & 7;
    int b = row / K_INST;
    int fc = first_cp[row];
    int safe = min(fc, N_HITS - 1);
    cp_emb4[(size_t)row * 8 + sub] = embed4[((size_t)b * N_HITS + safe) * 8 + sub];
    if (sub == 0) cp_beta[row] = beta[b * N_HITS + safe];
}

// ---------------------------------------------------------------------------
// Kernel 3: main pass. One thread per hit (x2), no cross-lane ops.
// Per-lane: 8 float4 loads of own embed row (L1 absorbs the 128B-stride
// pattern), 8 float4 loads of instance cp row (L2-resident 64KB table),
// full-lane BCE + 3 LDS-bin atomics.
// ---------------------------------------------------------------------------
__global__ __launch_bounds__(256) void k_main(
    const float*  __restrict__ beta,  const float4* __restrict__ embed4,
    const int*    __restrict__ sid_g, const int*    __restrict__ iscp_g,
    const float4* __restrict__ cp_emb4, const float* __restrict__ cp_beta,
    int* cnt_packed, float* seg_d2, float* seg_r,
    float* s_cp, float* s_ncp, float* s_bg) {
    __shared__ int   l_cnt[K_INST];
    __shared__ float l_d2[K_INST];
    __shared__ float l_r[K_INST];
    __shared__ float l_cb[K_INST];
    __shared__ float l_red[12];

    int b = blockIdx.y, tid = threadIdx.x;
    size_t bo = (size_t)b * N_HITS;
    int base = blockIdx.x * HITS_PB;

    for (int k = tid; k < K_INST; k += 256) {
        l_cnt[k] = 0; l_d2[k] = 0.f; l_r[k] = 0.f;
        l_cb[k] = cp_beta[b * K_INST + k];
    }
    __syncthreads();

    const float4* cpe = cp_emb4 + (size_t)b * K_INST * 8;
    float a_cp = 0.f, a_ncp = 0.f, a_bg = 0.f;

#pragma unroll
    for (int h = 0; h < HITS_PB / 256; ++h) {
        int i = base + h * 256 + tid;
        int s = sid_g[bo + i];
        int c = iscp_g[bo + i];
        float x = beta[bo + i];
        int sc = min(max(s, 0), K_INST - 1);
        const float4* ep  = embed4 + (bo + i) * 8;
        const float4* cpp = cpe + (size_t)sc * 8;

        float d2 = 0.f;
#pragma unroll
        for (int j = 0; j < 8; ++j) {
            float4 e = ep[j], ce = cpp[j];
            float dx = e.x - ce.x, dy = e.y - ce.y;
            float dz = e.z - ce.z, dw = e.w - ce.w;
            d2 += dx * dx + dy * dy + dz * dz + dw * dw;
        }

        bool cp = (c == 1), valid = (s >= 0), noncp = valid && !cp;
        float t = __expf(-fabsf(x));
        float bce = fmaxf(x, 0.f) - (cp ? x : 0.f) + __logf(1.f + t);
        if (cp) a_cp += bce; else if (noncp) a_ncp += bce; else a_bg += bce;
        if (valid) {
            atomicAdd(&l_cnt[s], cp ? (1 << 20) : 1);
            atomicAdd(&l_d2[s], d2);
            if (noncp) {
                float r = fmaxf(x + MARGIN - l_cb[s], 0.f);
                atomicAdd(&l_r[s], r);
            }
        }
    }

    // block-reduce the three BCE class sums
    for (int o = 32; o > 0; o >>= 1) {
        a_cp  += __shfl_down(a_cp, o);
        a_ncp += __shfl_down(a_ncp, o);
        a_bg  += __shfl_down(a_bg, o);
    }
    int wave = tid >> 6;
    if ((tid & 63) == 0) { l_red[wave] = a_cp; l_red[4 + wave] = a_ncp; l_red[8 + wave] = a_bg; }
    __syncthreads();
    if (tid == 0) {
        atomicAdd(&s_cp[b],  l_red[0] + l_red[1] + l_red[2]  + l_red[3]);
        atomicAdd(&s_ncp[b], l_red[4] + l_red[5] + l_red[6]  + l_red[7]);
        atomicAdd(&s_bg[b],  l_red[8] + l_red[9] + l_red[10] + l_red[11]);
    }
    // merge LDS bins to global
    for (int k = tid; k < K_INST; k += 256) {
        int   cv = l_cnt[k]; if (cv)        atomicAdd(&cnt_packed[b * K_INST + k], cv);
        float dv = l_d2[k];  if (dv != 0.f) atomicAdd(&seg_d2[b * K_INST + k], dv);
        float rv = l_r[k];   if (rv != 0.f) atomicAdd(&seg_r[b * K_INST + k], rv);
    }
}

// ---------------------------------------------------------------------------
// Kernel 4: fused tail: repulsion tiles + seg finalize + last-block combine.
// ---------------------------------------------------------------------------
__global__ __launch_bounds__(512) void k_tail(
    const float4* __restrict__ cp_emb4,
    const int* __restrict__ cnt_packed, const float* __restrict__ seg_d2,
    const float* __restrict__ seg_r, const int* __restrict__ first_cp,
    const int* __restrict__ pos_cnt, const float* __restrict__ s_cp,
    const float* __restrict__ s_ncp, const float* __restrict__ s_bg,
    float* attr_b, float* rank_b, float* nuniq_b, float* rep_b,
    int* ctr, float* out, int B) {
    int tid = threadIdx.x;
    int nrep = B * 16;

    if ((int)blockIdx.x < nrep) {
        __shared__ float4 tile[32 * 8];
        __shared__ float red[8];
        int b = blockIdx.x >> 4, t2 = blockIdx.x & 15;
        const float4* base = cp_emb4 + (size_t)b * K_INST * 8;
        float4 r0[8];
#pragma unroll
        for (int cc = 0; cc < 8; ++cc) r0[cc] = base[(size_t)tid * 8 + cc];
        if (tid < 256) tile[tid] = base[(size_t)t2 * 256 + tid];
        __syncthreads();
        float acc = 0.f;
        for (int j = 0; j < 32; ++j) {
            float d2 = 0.f;
#pragma unroll
            for (int cc = 0; cc < 8; ++cc) {
                float4 ev = tile[j * 8 + cc];
                float ax = r0[cc].x - ev.x, ay = r0[cc].y - ev.y;
                float az = r0[cc].z - ev.z, aw = r0[cc].w - ev.w;
                d2 += ax * ax + ay * ay + az * az + aw * aw;
            }
            acc += __expf(-d2);
        }
        for (int o = 32; o > 0; o >>= 1) acc += __shfl_down(acc, o);
        if ((tid & 63) == 0) red[tid >> 6] = acc;
        __syncthreads();
        if (tid == 0) {
            float t = 0.f;
            for (int w = 0; w < 8; ++w) t += red[w];
            atomicAdd(&rep_b[b], t);
        }
    } else {
        __shared__ float red2[3][8];
        int b = blockIdx.x - nrep, k = tid;
        int v = cnt_packed[b * K_INST + k];
        int ncp = v & 0xFFFFF, cpc = v >> 20;
        int counts = ncp + cpc;
        int fc = first_cp[b * K_INST + k];
        bool has_cp = fc < N_HITS, exists = counts > 0;
        float attr = (has_cp && exists) ? seg_d2[b * K_INST + k] / fmaxf((float)counts, 1.f) : 0.f;
        float rank = (cpc == 1 && ncp > 0) ? seg_r[b * K_INST + k] / fmaxf((float)ncp, 1.f) : 0.f;
        float uq = exists ? 1.f : 0.f;
        for (int o = 32; o > 0; o >>= 1) {
            attr += __shfl_down(attr, o);
            rank += __shfl_down(rank, o);
            uq   += __shfl_down(uq, o);
        }
        if ((k & 63) == 0) { red2[0][k >> 6] = attr; red2[1][k >> 6] = rank; red2[2][k >> 6] = uq; }
        __syncthreads();
        if (k == 0) {
            float a = 0.f, r = 0.f, u = 0.f;
            for (int w = 0; w < 8; ++w) { a += red2[0][w]; r += red2[1][w]; u += red2[2][w]; }
            attr_b[b] = a; rank_b[b] = r; nuniq_b[b] = u;
        }
    }

    __shared__ int is_last;
    __syncthreads();
    if (tid == 0) {
        __threadfence();
        int v = atomicAdd(ctr, 1);
        is_last = (v == (int)gridDim.x - 1);
    }
    __syncthreads();
    if (is_last) {
        __threadfence();
        if (tid < 64) {
            int b = tid;
            float loss = 0.f, bl = 0.f, at = 0.f, rp = 0.f;
            if (b < B) {
                float pos = (float)pos_cnt[b];
                float pw = ((float)N_HITS - pos) / (pos + 1e-6f);
                float bce = (pw * s_cp[b] + s_ncp[b] + 2.f * s_bg[b]) / (float)N_HITS;
                float rank = rank_b[b] / fmaxf(nuniq_b[b], 1.f);
                bl = bce + 2.f * rank;
                at = attr_b[b];
                rp = rep_b[b] / (float)(K_INST * K_INST);
                loss = bl + at + rp;
            }
            for (int o = 32; o > 0; o >>= 1) {
                loss += __shfl_down(loss, o);
                bl   += __shfl_down(bl, o);
                at   += __shfl_down(at, o);
                rp   += __shfl_down(rp, o);
            }
            if (tid == 0) {
                float inv = 1.f / (float)B;
                out[0] = loss * inv;
                out[1] = bl * inv;
                out[2] = at * inv;
                out[3] = rp * inv;
            }
        }
    }
}

// ---------------------------------------------------------------------------
extern "C" void kernel_launch(void* const* d_in, const int* in_sizes, int n_in,
                              void* d_out, int out_size, void* d_ws, size_t ws_size,
                              hipStream_t stream) {
    const float*  beta   = (const float*)d_in[0];
    const float*  embed  = (const float*)d_in[1];
    const int*    sid    = (const int*)d_in[2];
    const int*    iscp   = (const int*)d_in[3];
    float* out = (float*)d_out;

    int BN = in_sizes[0];          // B*N
    int B  = BN / N_HITS;          // 16
    int BK = B * K_INST;           // 8192

    char* ws = (char*)d_ws;
    int*   cnt_packed = (int*)ws;
    float* seg_d2     = (float*)(ws + 4 * (size_t)BK);
    float* seg_r      = (float*)(ws + 8 * (size_t)BK);
    float* scal       = (float*)(ws + 12 * (size_t)BK);
    int*   pos_cnt  = (int*)scal;
    float* s_cp     = scal + 1 * B;
    float* s_ncp    = scal + 2 * B;
    float* s_bg     = scal + 3 * B;
    float* attr_b   = scal + 4 * B;
    float* rank_b   = scal + 5 * B;
    float* nuniq_b  = scal + 6 * B;
    float* rep_b    = scal + 7 * B;
    int*   ctr      = (int*)(scal + 8 * B);
    size_t zbytes = 12 * (size_t)BK + 32 * (size_t)B + 16;
    int*    first_cp = (int*)(ws + zbytes);
    float*  cp_beta  = (float*)(ws + zbytes + 4 * (size_t)BK);
    float4* cp_emb4  = (float4*)(ws + zbytes + 8 * (size_t)BK);

    hipMemsetAsync(ws, 0, zbytes, stream);
    hipMemsetAsync(first_cp, 0x7F, 4 * (size_t)BK, stream);   // sentinel > N

    k_scan<<<dim3(32, B), 256, 0, stream>>>(sid, iscp, first_cp, pos_cnt);

    k_gather<<<(BK * 8 + 255) / 256, 256, 0, stream>>>(beta, (const float4*)embed,
                                                       first_cp, cp_beta, cp_emb4, B);

    k_main<<<dim3(BPB, B), 256, 0, stream>>>(beta, (const float4*)embed, sid, iscp,
                                             (const float4*)cp_emb4, cp_beta,
                                             cnt_packed, seg_d2, seg_r, s_cp, s_ncp, s_bg);

    k_tail<<<B * 16 + B, 512, 0, stream>>>(cp_emb4, cnt_packed, seg_d2, seg_r,
                                           first_cp, pos_cnt, s_cp, s_ncp, s_bg,
                                           attr_b, rank_b, nuniq_b, rep_b,
                                           ctr, out, B);
}